// Round 23
// baseline (129.918 us; speedup 1.0000x reference)
//
#include <hip/hip_runtime.h>
#include <hip/hip_bf16.h>

using f32x4  = __attribute__((ext_vector_type(4))) float;
using f32x16 = __attribute__((ext_vector_type(16))) float;
using bf16x8 = __attribute__((ext_vector_type(8))) __bf16;
using u16x8  = __attribute__((ext_vector_type(8))) unsigned short;
using u32x4  = __attribute__((ext_vector_type(4))) unsigned int;

#define DEV __device__ __forceinline__

constexpr int S_  = 4096;
constexpr int D_  = 1024;
constexpr int KD  = 1024;   // contraction dim for both GEMMs

// ---- ws layout (byte offsets) ----
constexpr size_t XB_OFF   = 0;                       // x bf16        [4096][1024]
constexpr size_t WQKV_OFF = 8388608;                 // Wqkv bf16     [3072][1024]
constexpr size_t WOUT_OFF = 14680064;                // out_w bf16    [1024][1024]
constexpr size_t QB_OFF   = 16777216;                // Q bf16        [16][4096][64]
constexpr size_t KB_OFF   = 25165824;                // K*scale bf16  [16][4096][64]
constexpr size_t VT_OFF   = 33554432;                // V^T bf16      [16][64][4096]
constexpr size_t CTX_OFF  = 41943040;                // ctx bf16      [4096][1024]

DEV unsigned short f2bf(float f) {
  __hip_bfloat16 h = __float2bfloat16(f);
  return __builtin_bit_cast(unsigned short, h);
}

DEV void gl_lds16(const void* g, void* l) {
  __builtin_amdgcn_global_load_lds(
      (const __attribute__((address_space(1))) void*)g,
      (__attribute__((address_space(3))) void*)l, 16, 0, 0);
}

DEV f32x4 mfma16(bf16x8 a, bf16x8 b, f32x4 c) {
  return __builtin_amdgcn_mfma_f32_16x16x32_bf16(a, b, c, 0, 0, 0);
}
DEV f32x16 mfma32(bf16x8 a, bf16x8 b, f32x16 c) {
  return __builtin_amdgcn_mfma_f32_32x32x16_bf16(a, b, c, 0, 0, 0);
}
DEV unsigned cvtpk(float lo, float hi) {
  unsigned r;
  asm("v_cvt_pk_bf16_f32 %0, %1, %2" : "=v"(r) : "v"(lo), "v"(hi));
  return r;
}
DEV float exp2_fast(float x) {   // 2^x, -inf -> 0
  float r;
  asm("v_exp_f32 %0, %1" : "=v"(r) : "v"(x));
  return r;
}
// swap a's hi 32 lanes with b's lo 32 lanes (both distinct SSA values!)
DEV void pl32(unsigned& a, unsigned& b) {
  asm("v_permlane32_swap_b32 %0, %1" : "+v"(a), "+v"(b));
}

// ---------------- fused f32 -> bf16 conversion of all three inputs ----------------
__global__ void cvt_all_k(const float* __restrict__ x,
                          const float* __restrict__ wq,
                          const float* __restrict__ wo,
                          unsigned short* __restrict__ xb,
                          unsigned short* __restrict__ wqb,
                          unsigned short* __restrict__ wob) {
  // units of 8 elems: x 524288 | wqkv 393216 | wout 131072 = 1048576 total
  for (int u = blockIdx.x * 256 + threadIdx.x; u < 1048576; u += 2048 * 256) {
    const float* s; unsigned short* d; int off;
    if (u < 524288)      { s = x;  d = xb;  off = u; }
    else if (u < 917504) { s = wq; d = wqb; off = u - 524288; }
    else                 { s = wo; d = wob; off = u - 917504; }
    const float4* s4 = (const float4*)s;
    float4 a = s4[2 * off], b = s4[2 * off + 1];
    u16x8 o;
    o[0] = f2bf(a.x); o[1] = f2bf(a.y); o[2] = f2bf(a.z); o[3] = f2bf(a.w);
    o[4] = f2bf(b.x); o[5] = f2bf(b.y); o[6] = f2bf(b.z); o[7] = f2bf(b.w);
    ((u16x8*)d)[off] = o;
  }
}

// ---------------- QKV GEMM C = A(MxK) * Bt(NxK)^T, 128x128 tile, BK=32 ----------------
// 512 thr = 8 waves (wave-tile 64x32, acc[4][2], 8 MFMA/iter/wave), 24 waves/CU.
// Staging: 1 gl_lds16 each for A and B per thread (8 KB tile each).
__global__ __launch_bounds__(512)
void gemm_qkv_k(const unsigned short* __restrict__ A,
                const unsigned short* __restrict__ Bt,
                const float* __restrict__ bias,
                unsigned short* __restrict__ qb,
                unsigned short* __restrict__ kb,
                unsigned short* __restrict__ vt) {
  __shared__ unsigned short As[2][4096];
  __shared__ unsigned short Bs[2][4096];
  const int t = threadIdx.x;
  const int w = t >> 6, l = t & 63;
  const int lr = l & 15, lg = l >> 4, lk = lg * 8;
  const int m0 = blockIdx.y * 128, n0 = blockIdx.x * 128;
  const int wm = (w >> 2) * 64, wn = (w & 3) * 32;

  f32x4 acc[4][2] = {};

  const int srow = t >> 2;            // 0..127
  const int scolb = (t & 3) << 4;     // byte col 0/16/32/48
  const char* Ag = (const char*)A + (size_t)(m0 + srow) * (KD * 2) + scolb;
  const char* Bg = (const char*)Bt + (size_t)(n0 + srow) * (KD * 2) + scolb;

  auto stage = [&](int buf, int kt) {
    gl_lds16(Ag + kt * 64, (char*)&As[buf][0] + t * 16);
    gl_lds16(Bg + kt * 64, (char*)&Bs[buf][0] + t * 16);
  };

  stage(0, 0);
  for (int kt = 0; kt < KD / 32; ++kt) {
    __syncthreads();
    if (kt + 1 < KD / 32) stage((kt + 1) & 1, kt + 1);
    const int buf = kt & 1;

    bf16x8 a[4], bb[2];
#pragma unroll
    for (int mi = 0; mi < 4; ++mi)
      a[mi] = *(const bf16x8*)&As[buf][(wm + mi * 16 + lr) * 32 + lk];
#pragma unroll
    for (int ni = 0; ni < 2; ++ni)
      bb[ni] = *(const bf16x8*)&Bs[buf][(wn + ni * 16 + lr) * 32 + lk];
#pragma unroll
    for (int mi = 0; mi < 4; ++mi)
#pragma unroll
      for (int ni = 0; ni < 2; ++ni)
        acc[mi][ni] = mfma16(a[mi], bb[ni], acc[mi][ni]);
  }

  const int r0 = lg * 4;
  const int which = n0 >> 10;
  // K pre-scale folds softmax 1/sqrt(64) AND log2(e) (exp done as exp2)
  const float kscale = 0.125f * 1.44269504088896f;
#pragma unroll
  for (int mi = 0; mi < 4; ++mi) {
    const int sbase = m0 + wm + mi * 16 + r0;
#pragma unroll
    for (int ni = 0; ni < 2; ++ni) {
      const int e = n0 + wn + ni * 16 + lr;
      const float bv = bias[e];
      const int h = (e & 1023) >> 6, dd = e & 63;
#pragma unroll
      for (int r = 0; r < 4; ++r) {
        const float v = acc[mi][ni][r] + bv;
        const int sr = sbase + r;
        if (which == 0)      qb[((size_t)(h * S_ + sr)) * 64 + dd] = f2bf(v);
        else if (which == 1) kb[((size_t)(h * S_ + sr)) * 64 + dd] = f2bf(v * kscale);
        else                 vt[((size_t)(h * 64 + dd)) * S_ + sr] = f2bf(v);
      }
    }
  }
}

// ---------------- out-proj GEMM, 128x64 tile, 512 thr = 8 waves ----------------
__global__ __launch_bounds__(512)
void gemm_proj_k(const unsigned short* __restrict__ A,
                 const unsigned short* __restrict__ Bt,
                 const float* __restrict__ bias,
                 float* __restrict__ outf) {
  __shared__ unsigned short As[2][4096];   // 128 x 32
  __shared__ unsigned short Bs[2][2048];   // 64 x 32
  const int t = threadIdx.x;
  const int w = t >> 6, l = t & 63;
  const int lr = l & 15, lg = l >> 4, lk = lg * 8;
  const int m0 = blockIdx.y * 128, n0 = blockIdx.x * 64;
  const int wm = (w >> 1) * 32, wn = (w & 1) * 32;

  f32x4 acc[2][2] = {};

  const int srow = t >> 2;            // 0..127 (A); 0..63 used for B
  const int scolb = (t & 3) << 4;
  const char* Ag = (const char*)A + (size_t)(m0 + srow) * (KD * 2) + scolb;
  const char* Bg = (const char*)Bt + (size_t)(n0 + (srow & 63)) * (KD * 2) + scolb;

  auto stage = [&](int buf, int kt) {
    gl_lds16(Ag + kt * 64, (char*)&As[buf][0] + t * 16);
    if (t < 256) gl_lds16(Bg + kt * 64, (char*)&Bs[buf][0] + t * 16);
  };

  stage(0, 0);
  for (int kt = 0; kt < KD / 32; ++kt) {
    __syncthreads();
    if (kt + 1 < KD / 32) stage((kt + 1) & 1, kt + 1);
    const int buf = kt & 1;

    bf16x8 a[2], bb[2];
#pragma unroll
    for (int mi = 0; mi < 2; ++mi)
      a[mi] = *(const bf16x8*)&As[buf][(wm + mi * 16 + lr) * 32 + lk];
#pragma unroll
    for (int ni = 0; ni < 2; ++ni)
      bb[ni] = *(const bf16x8*)&Bs[buf][(wn + ni * 16 + lr) * 32 + lk];
#pragma unroll
    for (int mi = 0; mi < 2; ++mi)
#pragma unroll
      for (int ni = 0; ni < 2; ++ni)
        acc[mi][ni] = mfma16(a[mi], bb[ni], acc[mi][ni]);
  }

  const int r0 = lg * 4;
#pragma unroll
  for (int mi = 0; mi < 2; ++mi) {
    const int sbase = m0 + wm + mi * 16 + r0;
#pragma unroll
    for (int ni = 0; ni < 2; ++ni) {
      const int e = n0 + wn + ni * 16 + lr;
      const float bv = bias[e];
#pragma unroll
      for (int r = 0; r < 4; ++r)
        outf[(size_t)(sbase + r) * D_ + e] = acc[mi][ni][r] + bv;
    }
  }
}

// ---------------- causal flash attention, swapped-QK^T 32x32, kv-split-2 ----------------
// 512 single-task blocks (grid 32x16), 512 thr = 8 waves, LDS 64 KB ->
// 2 blocks/CU. b = x + 32y; h = ((b&7)<<1)|((b>>3)&1); qi = b>>4;
// bi = qi<16 ? 31-qi : qi-16 (co-resident heavy+light pair sums 33 iters).
// r14-verified inner loop: blocked kv-split (niter=bi+1/group), K+V dbuf
// XOR-swizzled, fixed-shift softmax, fast/slow paths, setprio, LDS combine.
// NEW: softmax denominator via MFMA — sumacc = mfma32(ones, pf, sumacc)
// replaces the VALU add-tree + cross-half permlane (the MFMA K-dim spans
// both lane-halves, so the hi/lo combine happens inside the matrix op;
// masked entries are exp2(-inf)=0 and contribute nothing).
__global__ __launch_bounds__(512, 4)
void attn_k(const unsigned short* __restrict__ Qb,
            const unsigned short* __restrict__ Kb,
            const unsigned short* __restrict__ Vt,
            unsigned short* __restrict__ ctx) {
  __shared__ char smem[65536];
  // [0,32768): K tiles [g][buf][8192]; [32768,65536): V tiles [g][buf][8192]
  // combine overlay (after post-loop barrier): f32 slot[(w*64+l)] stride 36

  const int t = threadIdx.x;
  const int w8 = t >> 6;              // 0..7
  const int g  = w8 >> 2;             // kv-split group
  const int w  = w8 & 3;              // q sub-tile
  const int l = t & 63, lq = l & 31, hi = l >> 5;
  const int b = blockIdx.x + (blockIdx.y << 5);      // hardware linear id
  const int h = ((b & 7) << 1) | ((b >> 3) & 1);     // XCD(b)=b%8 heuristic
  const int qi = b >> 4;                              // 0..31
  const int bi = qi < 16 ? (31 - qi) : (qi - 16);     // concurrent pairing

  // staging: thread-half sg stages group sg's buffers
  const int sg = t >> 8;
  const int ts = t & 255;
  const int srow = ts >> 3;
  const int ssw  = ((ts & 7) << 4) ^ ((srow & 7) << 4);
  const char* Kg0 = (const char*)Kb + (size_t)(h * S_) * 128;
  const char* Vg0 = (const char*)Vt + (size_t)(h * 64) * (size_t)(S_ * 2);

  const int q0 = bi * 128;
  const int qrow = q0 + w * 32 + lq;
  const int qwmin = q0 + w * 32, qwmax = qwmin + 31;
  const int niter = bi + 1;           // kv tiles per group (blocked split)

  // Q fragments: B-operand of S^T mfma: lane holds Q[q=lq][d0*16 + hi*8 + e]
  const unsigned short* Qr = Qb + ((size_t)(h * S_ + qrow)) * 64;
  bf16x8 qf[4];
#pragma unroll
  for (int d0 = 0; d0 < 4; ++d0)
    qf[d0] = *(const bf16x8*)(Qr + d0 * 16 + hi * 8);

  // all-ones bf16 A-operand for the denominator MFMA
  u16x8 ou; 
#pragma unroll
  for (int j = 0; j < 8; ++j) ou[j] = 0x3F80;
  const bf16x8 onesf = __builtin_bit_cast(bf16x8, ou);

  f32x16 cacc[2] = {};      // ctx^T[d][q], d-blocks 0..31 / 32..63
  f32x16 sumacc = {};       // denominator: every row = sum_kv P[kv][q=lq]

  auto stage = [&](int buf, int tl) {   // stage tile tl into group sg's buf
    const int kv0 = tl * 64;
    char* kd = smem + sg * 16384 + buf * 8192;
    const char* Kg = Kg0 + (size_t)kv0 * 128;
    gl_lds16(Kg + (size_t)srow * 128 + ssw,        kd + ts * 16);
    gl_lds16(Kg + (size_t)(32 + srow) * 128 + ssw, kd + 4096 + ts * 16);
    char* vd = smem + 32768 + sg * 16384 + buf * 8192;
    const char* Vg = Vg0 + (size_t)kv0 * 2;
    gl_lds16(Vg + (size_t)srow * (S_ * 2) + ssw,        vd + ts * 16);
    gl_lds16(Vg + (size_t)(32 + srow) * (S_ * 2) + ssw, vd + 4096 + ts * 16);
  };

  int cur = 0;
  stage(0, sg * niter);

  for (int it = 0; it < niter; ++it) {
    __syncthreads();
    if (it + 1 < niter) stage(cur ^ 1, it + 1 + sg * niter);
    const char* Kt = smem + g * 16384 + cur * 8192;
    const char* Vl = smem + 32768 + g * 16384 + cur * 8192;
    const int tl = it + g * niter;

    if (tl * 64 + 63 <= qwmin) {
      // ======== FAST PATH: full 64-kv tile, no mask, fused sub-tiles ========
      f32x16 st0, st1;
#pragma unroll
      for (int r = 0; r < 16; ++r) { st0[r] = -8.0f; st1[r] = -8.0f; }
      const char* kb0 = Kt + lq * 128;
      const char* kb1 = Kt + (32 + lq) * 128;
      const int ksw = (lq & 7) << 4;
      __builtin_amdgcn_s_setprio(1);
#pragma unroll
      for (int d0 = 0; d0 < 4; ++d0) {
        bf16x8 kf0 = *(const bf16x8*)(kb0 + ((d0 * 32 + hi * 16) ^ ksw));
        bf16x8 kf1 = *(const bf16x8*)(kb1 + ((d0 * 32 + hi * 16) ^ ksw));
        st0 = mfma32(kf0, qf[d0], st0);
        st1 = mfma32(kf1, qf[d0], st1);
      }
      __builtin_amdgcn_s_setprio(0);

#pragma unroll
      for (int r = 0; r < 16; ++r) { st0[r] = exp2_fast(st0[r]); st1[r] = exp2_fast(st1[r]); }

      unsigned x0 = cvtpk(st0[0], st0[1]),   x1 = cvtpk(st0[2], st0[3]);
      unsigned y0 = cvtpk(st0[4], st0[5]),   y1 = cvtpk(st0[6], st0[7]);
      pl32(x0, y0); pl32(x1, y1);
      u32x4 f00 = {x0, x1, y0, y1};
      bf16x8 pf00 = __builtin_bit_cast(bf16x8, f00);
      unsigned x2 = cvtpk(st0[8], st0[9]),   x3 = cvtpk(st0[10], st0[11]);
      unsigned y2 = cvtpk(st0[12], st0[13]), y3 = cvtpk(st0[14], st0[15]);
      pl32(x2, y2); pl32(x3, y3);
      u32x4 f01 = {x2, x3, y2, y3};
      bf16x8 pf01 = __builtin_bit_cast(bf16x8, f01);
      unsigned u0 = cvtpk(st1[0], st1[1]),    u1 = cvtpk(st1[2], st1[3]);
      unsigned v0w = cvtpk(st1[4], st1[5]),   v1w = cvtpk(st1[6], st1[7]);
      pl32(u0, v0w); pl32(u1, v1w);
      u32x4 f10 = {u0, u1, v0w, v1w};
      bf16x8 pf10 = __builtin_bit_cast(bf16x8, f10);
      unsigned u2 = cvtpk(st1[8], st1[9]),    u3 = cvtpk(st1[10], st1[11]);
      unsigned v2w = cvtpk(st1[12], st1[13]), v3w = cvtpk(st1[14], st1[15]);
      pl32(u2, v2w); pl32(u3, v3w);
      u32x4 f11 = {u2, u3, v2w, v3w};
      bf16x8 pf11 = __builtin_bit_cast(bf16x8, f11);

      __builtin_amdgcn_s_setprio(1);
      sumacc = mfma32(onesf, pf00, sumacc);
      sumacc = mfma32(onesf, pf01, sumacc);
      sumacc = mfma32(onesf, pf10, sumacc);
      sumacc = mfma32(onesf, pf11, sumacc);
#pragma unroll
      for (int db = 0; db < 2; ++db) {
        const int dr = db * 32 + lq;
        const char* vbase = Vl + dr * 128;
        const int vsw = (dr & 7) << 4;
        bf16x8 va = *(const bf16x8*)(vbase + ((hi * 16) ^ vsw));
        bf16x8 vb = *(const bf16x8*)(vbase + ((32 + hi * 16) ^ vsw));
        bf16x8 vc = *(const bf16x8*)(vbase + ((64 + hi * 16) ^ vsw));
        bf16x8 vd = *(const bf16x8*)(vbase + ((96 + hi * 16) ^ vsw));
        cacc[db] = mfma32(va, pf00, cacc[db]);
        cacc[db] = mfma32(vb, pf01, cacc[db]);
        cacc[db] = mfma32(vc, pf10, cacc[db]);
        cacc[db] = mfma32(vd, pf11, cacc[db]);
      }
      __builtin_amdgcn_s_setprio(0);
    } else {
      // ======== SLOW PATH: diag-straddling / partially skipped tile ========
#pragma unroll
      for (int kvh = 0; kvh < 2; ++kvh) {
        const int kv0s = tl * 64 + kvh * 32;
        if (kv0s > qwmax) continue;   // wave-uniform: fully masked sub-tile

        f32x16 st;
#pragma unroll
        for (int r = 0; r < 16; ++r) st[r] = -8.0f;   // fixed softmax shift
        const int kr = kvh * 32 + lq;
        const char* kbase = Kt + kr * 128;
        const int ksw = (kr & 7) << 4;
#pragma unroll
        for (int d0 = 0; d0 < 4; ++d0) {
          bf16x8 kf = *(const bf16x8*)(kbase + ((d0 * 32 + hi * 16) ^ ksw));
          st = mfma32(kf, qf[d0], st);
        }

        if (kv0s + 31 > qwmin) {
#pragma unroll
          for (int r = 0; r < 16; ++r) {
            const int kvg = kv0s + (r & 3) + 8 * (r >> 2) + 4 * hi;
            if (kvg > qrow) st[r] = -INFINITY;
          }
        }

#pragma unroll
        for (int r = 0; r < 16; ++r) st[r] = exp2_fast(st[r]);

        unsigned x0 = cvtpk(st[0], st[1]),   x1 = cvtpk(st[2], st[3]);
        unsigned y0 = cvtpk(st[4], st[5]),   y1 = cvtpk(st[6], st[7]);
        pl32(x0, y0); pl32(x1, y1);
        u32x4 f0 = {x0, x1, y0, y1};
        bf16x8 pf0 = __builtin_bit_cast(bf16x8, f0);
        unsigned x2 = cvtpk(st[8], st[9]),   x3 = cvtpk(st[10], st[11]);
        unsigned y2 = cvtpk(st[12], st[13]), y3 = cvtpk(st[14], st[15]);
        pl32(x2, y2); pl32(x3, y3);
        u32x4 f1 = {x2, x3, y2, y3};
        bf16x8 pf1 = __builtin_bit_cast(bf16x8, f1);

        sumacc = mfma32(onesf, pf0, sumacc);
        sumacc = mfma32(onesf, pf1, sumacc);
#pragma unroll
        for (int db = 0; db < 2; ++db) {
          const int dr = db * 32 + lq;
          const char* vbase = Vl + dr * 128;
          const int vsw = (dr & 7) << 4;
          bf16x8 v0 = *(const bf16x8*)(vbase + ((kvh * 64 + hi * 16) ^ vsw));
          bf16x8 v1 = *(const bf16x8*)(vbase + ((kvh * 64 + 32 + hi * 16) ^ vsw));
          cacc[db] = mfma32(v0, pf0, cacc[db]);
          cacc[db] = mfma32(v1, pf1, cacc[db]);
        }
      }
    }
    cur ^= 1;
  }

  // ---- combine group partials: plain adds (fixed shift -> no scaling) ----
  __syncthreads();                  // all staged loads drained; overlay safe
  float* slot = (float*)smem + (size_t)(w * 64 + l) * 36;
  const float lsum = sumacc[0];     // every row of sumacc equals sum_kv P[kv][lq]
  if (g == 1) {
    slot[0] = lsum;
#pragma unroll
    for (int j = 0; j < 16; ++j) { slot[1 + j] = cacc[0][j]; slot[17 + j] = cacc[1][j]; }
  }
  __syncthreads();
  if (g == 0) {
    const float inv = 1.0f / (lsum + slot[0]);
    unsigned short* base = ctx + (size_t)qrow * D_ + h * 64;
#pragma unroll
    for (int db = 0; db < 2; ++db)
#pragma unroll
      for (int r = 0; r < 16; r += 2) {
        const float o0 = (cacc[db][r]     + slot[1 + db * 16 + r])     * inv;
        const float o1 = (cacc[db][r + 1] + slot[1 + db * 16 + r + 1]) * inv;
        const unsigned wv = cvtpk(o0, o1);
        const int d = (r & 3) + 8 * (r >> 2) + 4 * hi + 32 * db;
        *(unsigned*)(base + d) = wv;
      }
  }
}

extern "C" void kernel_launch(void* const* d_in, const int* in_sizes, int n_in,
                              void* d_out, int out_size, void* d_ws, size_t ws_size,
                              hipStream_t stream) {
  const float* x      = (const float*)d_in[0];
  const float* Wqkv_w = (const float*)d_in[1];
  const float* Wqkv_b = (const float*)d_in[2];
  const float* out_w  = (const float*)d_in[3];
  const float* out_b  = (const float*)d_in[4];
  float* out = (float*)d_out;
  char* ws = (char*)d_ws;

  unsigned short* xb    = (unsigned short*)(ws + XB_OFF);
  unsigned short* wqkvb = (unsigned short*)(ws + WQKV_OFF);
  unsigned short* woutb = (unsigned short*)(ws + WOUT_OFF);
  unsigned short* Qb    = (unsigned short*)(ws + QB_OFF);
  unsigned short* Kb    = (unsigned short*)(ws + KB_OFF);
  unsigned short* Vt    = (unsigned short*)(ws + VT_OFF);
  unsigned short* ctx   = (unsigned short*)(ws + CTX_OFF);

  cvt_all_k<<<2048, 256, 0, stream>>>(x, Wqkv_w, out_w, xb, wqkvb, woutb);

  gemm_qkv_k<<<dim3(24, 32), 512, 0, stream>>>(xb, wqkvb, Wqkv_b, Qb, Kb, Vt);

  attn_k<<<dim3(32, 16), 512, 0, stream>>>(Qb, Kb, Vt, ctx);

  gemm_proj_k<<<dim3(16, 32), 512, 0, stream>>>(ctx, woutb, out_b, out);
}

// Round 24
// 120.077 us; speedup vs baseline: 1.0820x; 1.0820x over previous
//
#include <hip/hip_runtime.h>
#include <hip/hip_bf16.h>

using f32x4  = __attribute__((ext_vector_type(4))) float;
using f32x16 = __attribute__((ext_vector_type(16))) float;
using bf16x8 = __attribute__((ext_vector_type(8))) __bf16;
using u16x8  = __attribute__((ext_vector_type(8))) unsigned short;
using u32x4  = __attribute__((ext_vector_type(4))) unsigned int;

#define DEV __device__ __forceinline__

constexpr int S_  = 4096;
constexpr int D_  = 1024;
constexpr int KD  = 1024;   // contraction dim for both GEMMs

// ---- ws layout (byte offsets) ----
constexpr size_t XB_OFF   = 0;                       // x bf16        [4096][1024]
constexpr size_t WQKV_OFF = 8388608;                 // Wqkv bf16     [3072][1024]
constexpr size_t WOUT_OFF = 14680064;                // out_w bf16    [1024][1024]
constexpr size_t QB_OFF   = 16777216;                // Q bf16        [16][4096][64]
constexpr size_t KB_OFF   = 25165824;                // K*scale bf16  [16][4096][64]
constexpr size_t VT_OFF   = 33554432;                // V^T bf16      [16][64][4096]
constexpr size_t CTX_OFF  = 41943040;                // ctx bf16      [4096][1024]

DEV unsigned short f2bf(float f) {
  __hip_bfloat16 h = __float2bfloat16(f);
  return __builtin_bit_cast(unsigned short, h);
}

DEV void gl_lds16(const void* g, void* l) {
  __builtin_amdgcn_global_load_lds(
      (const __attribute__((address_space(1))) void*)g,
      (__attribute__((address_space(3))) void*)l, 16, 0, 0);
}

DEV f32x4 mfma16(bf16x8 a, bf16x8 b, f32x4 c) {
  return __builtin_amdgcn_mfma_f32_16x16x32_bf16(a, b, c, 0, 0, 0);
}
DEV f32x16 mfma32(bf16x8 a, bf16x8 b, f32x16 c) {
  return __builtin_amdgcn_mfma_f32_32x32x16_bf16(a, b, c, 0, 0, 0);
}
DEV unsigned cvtpk(float lo, float hi) {
  unsigned r;
  asm("v_cvt_pk_bf16_f32 %0, %1, %2" : "=v"(r) : "v"(lo), "v"(hi));
  return r;
}
DEV float exp2_fast(float x) {   // 2^x, -inf -> 0
  float r;
  asm("v_exp_f32 %0, %1" : "=v"(r) : "v"(x));
  return r;
}
// swap a's hi 32 lanes with b's lo 32 lanes (both distinct SSA values!)
DEV void pl32(unsigned& a, unsigned& b) {
  asm("v_permlane32_swap_b32 %0, %1" : "+v"(a), "+v"(b));
}
DEV float xhalf_add(float x) {   // own + lane^32; forced-distinct copy
  float y;
  asm("v_mov_b32 %0, %1" : "=v"(y) : "v"(x));
  unsigned a = __builtin_bit_cast(unsigned, x), b = __builtin_bit_cast(unsigned, y);
  pl32(a, b);
  return __builtin_bit_cast(float, a) + __builtin_bit_cast(float, b);
}

// ---------------- fused f32 -> bf16 conversion of all three inputs ----------------
__global__ void cvt_all_k(const float* __restrict__ x,
                          const float* __restrict__ wq,
                          const float* __restrict__ wo,
                          unsigned short* __restrict__ xb,
                          unsigned short* __restrict__ wqb,
                          unsigned short* __restrict__ wob) {
  // units of 8 elems: x 524288 | wqkv 393216 | wout 131072 = 1048576 total
  for (int u = blockIdx.x * 256 + threadIdx.x; u < 1048576; u += 2048 * 256) {
    const float* s; unsigned short* d; int off;
    if (u < 524288)      { s = x;  d = xb;  off = u; }
    else if (u < 917504) { s = wq; d = wqb; off = u - 524288; }
    else                 { s = wo; d = wob; off = u - 917504; }
    const float4* s4 = (const float4*)s;
    float4 a = s4[2 * off], b = s4[2 * off + 1];
    u16x8 o;
    o[0] = f2bf(a.x); o[1] = f2bf(a.y); o[2] = f2bf(a.z); o[3] = f2bf(a.w);
    o[4] = f2bf(b.x); o[5] = f2bf(b.y); o[6] = f2bf(b.z); o[7] = f2bf(b.w);
    ((u16x8*)d)[off] = o;
  }
}

// ---------------- QKV GEMM C = A(MxK) * Bt(NxK)^T, 128x128 tile, BK=32 ----------------
// 512 thr = 8 waves (wave-tile 64x32, acc[4][2], 8 MFMA/iter/wave), 24 waves/CU.
// Staging: 1 gl_lds16 each for A and B per thread (8 KB tile each).
__global__ __launch_bounds__(512)
void gemm_qkv_k(const unsigned short* __restrict__ A,
                const unsigned short* __restrict__ Bt,
                const float* __restrict__ bias,
                unsigned short* __restrict__ qb,
                unsigned short* __restrict__ kb,
                unsigned short* __restrict__ vt) {
  __shared__ unsigned short As[2][4096];
  __shared__ unsigned short Bs[2][4096];
  const int t = threadIdx.x;
  const int w = t >> 6, l = t & 63;
  const int lr = l & 15, lg = l >> 4, lk = lg * 8;
  const int m0 = blockIdx.y * 128, n0 = blockIdx.x * 128;
  const int wm = (w >> 2) * 64, wn = (w & 3) * 32;

  f32x4 acc[4][2] = {};

  const int srow = t >> 2;            // 0..127
  const int scolb = (t & 3) << 4;     // byte col 0/16/32/48
  const char* Ag = (const char*)A + (size_t)(m0 + srow) * (KD * 2) + scolb;
  const char* Bg = (const char*)Bt + (size_t)(n0 + srow) * (KD * 2) + scolb;

  auto stage = [&](int buf, int kt) {
    gl_lds16(Ag + kt * 64, (char*)&As[buf][0] + t * 16);
    gl_lds16(Bg + kt * 64, (char*)&Bs[buf][0] + t * 16);
  };

  stage(0, 0);
  for (int kt = 0; kt < KD / 32; ++kt) {
    __syncthreads();
    if (kt + 1 < KD / 32) stage((kt + 1) & 1, kt + 1);
    const int buf = kt & 1;

    bf16x8 a[4], bb[2];
#pragma unroll
    for (int mi = 0; mi < 4; ++mi)
      a[mi] = *(const bf16x8*)&As[buf][(wm + mi * 16 + lr) * 32 + lk];
#pragma unroll
    for (int ni = 0; ni < 2; ++ni)
      bb[ni] = *(const bf16x8*)&Bs[buf][(wn + ni * 16 + lr) * 32 + lk];
#pragma unroll
    for (int mi = 0; mi < 4; ++mi)
#pragma unroll
      for (int ni = 0; ni < 2; ++ni)
        acc[mi][ni] = mfma16(a[mi], bb[ni], acc[mi][ni]);
  }

  const int r0 = lg * 4;
  const int which = n0 >> 10;
  // K pre-scale folds softmax 1/sqrt(64) AND log2(e) (exp done as exp2)
  const float kscale = 0.125f * 1.44269504088896f;
#pragma unroll
  for (int mi = 0; mi < 4; ++mi) {
    const int sbase = m0 + wm + mi * 16 + r0;
#pragma unroll
    for (int ni = 0; ni < 2; ++ni) {
      const int e = n0 + wn + ni * 16 + lr;
      const float bv = bias[e];
      const int h = (e & 1023) >> 6, dd = e & 63;
#pragma unroll
      for (int r = 0; r < 4; ++r) {
        const float v = acc[mi][ni][r] + bv;
        const int sr = sbase + r;
        if (which == 0)      qb[((size_t)(h * S_ + sr)) * 64 + dd] = f2bf(v);
        else if (which == 1) kb[((size_t)(h * S_ + sr)) * 64 + dd] = f2bf(v * kscale);
        else                 vt[((size_t)(h * 64 + dd)) * S_ + sr] = f2bf(v);
      }
    }
  }
}

// ---------------- out-proj GEMM, 128x64 tile, 512 thr = 8 waves ----------------
__global__ __launch_bounds__(512)
void gemm_proj_k(const unsigned short* __restrict__ A,
                 const unsigned short* __restrict__ Bt,
                 const float* __restrict__ bias,
                 float* __restrict__ outf) {
  __shared__ unsigned short As[2][4096];   // 128 x 32
  __shared__ unsigned short Bs[2][2048];   // 64 x 32
  const int t = threadIdx.x;
  const int w = t >> 6, l = t & 63;
  const int lr = l & 15, lg = l >> 4, lk = lg * 8;
  const int m0 = blockIdx.y * 128, n0 = blockIdx.x * 64;
  const int wm = (w >> 1) * 32, wn = (w & 1) * 32;

  f32x4 acc[2][2] = {};

  const int srow = t >> 2;            // 0..127 (A); 0..63 used for B
  const int scolb = (t & 3) << 4;
  const char* Ag = (const char*)A + (size_t)(m0 + srow) * (KD * 2) + scolb;
  const char* Bg = (const char*)Bt + (size_t)(n0 + (srow & 63)) * (KD * 2) + scolb;

  auto stage = [&](int buf, int kt) {
    gl_lds16(Ag + kt * 64, (char*)&As[buf][0] + t * 16);
    if (t < 256) gl_lds16(Bg + kt * 64, (char*)&Bs[buf][0] + t * 16);
  };

  stage(0, 0);
  for (int kt = 0; kt < KD / 32; ++kt) {
    __syncthreads();
    if (kt + 1 < KD / 32) stage((kt + 1) & 1, kt + 1);
    const int buf = kt & 1;

    bf16x8 a[2], bb[2];
#pragma unroll
    for (int mi = 0; mi < 2; ++mi)
      a[mi] = *(const bf16x8*)&As[buf][(wm + mi * 16 + lr) * 32 + lk];
#pragma unroll
    for (int ni = 0; ni < 2; ++ni)
      bb[ni] = *(const bf16x8*)&Bs[buf][(wn + ni * 16 + lr) * 32 + lk];
#pragma unroll
    for (int mi = 0; mi < 2; ++mi)
#pragma unroll
      for (int ni = 0; ni < 2; ++ni)
        acc[mi][ni] = mfma16(a[mi], bb[ni], acc[mi][ni]);
  }

  const int r0 = lg * 4;
#pragma unroll
  for (int mi = 0; mi < 2; ++mi) {
    const int sbase = m0 + wm + mi * 16 + r0;
#pragma unroll
    for (int ni = 0; ni < 2; ++ni) {
      const int e = n0 + wn + ni * 16 + lr;
      const float bv = bias[e];
#pragma unroll
      for (int r = 0; r < 4; ++r)
        outf[(size_t)(sbase + r) * D_ + e] = acc[mi][ni][r] + bv;
    }
  }
}

// ---------------- causal flash attention, swapped-QK^T 32x32, kv-split-2 ----------------
// 512 single-task blocks (grid 32x16), 512 thr = 8 waves, LDS 64 KB ->
// 2 blocks/CU. b = x + 32y; h = ((b&7)<<1)|((b>>3)&1); qi = b>>4;
// bi = qi<16 ? 31-qi : qi-16 (co-resident heavy+light pair sums 33 iters).
// r14-verified inner loop: blocked kv-split (niter=bi+1/group), K+V dbuf
// XOR-swizzled, fixed-shift softmax, fast/slow paths, setprio, LDS combine.
// (r23's MFMA row-sum reverted: serial accumulator-dependent MFMA chain
// exposed MFMA latency and serialized against PV — VALU tree is cheaper.)
__global__ __launch_bounds__(512, 4)
void attn_k(const unsigned short* __restrict__ Qb,
            const unsigned short* __restrict__ Kb,
            const unsigned short* __restrict__ Vt,
            unsigned short* __restrict__ ctx) {
  __shared__ char smem[65536];
  // [0,32768): K tiles [g][buf][8192]; [32768,65536): V tiles [g][buf][8192]
  // combine overlay (after post-loop barrier): f32 slot[(w*64+l)] stride 36

  const int t = threadIdx.x;
  const int w8 = t >> 6;              // 0..7
  const int g  = w8 >> 2;             // kv-split group
  const int w  = w8 & 3;              // q sub-tile
  const int l = t & 63, lq = l & 31, hi = l >> 5;
  const int b = blockIdx.x + (blockIdx.y << 5);      // hardware linear id
  const int h = ((b & 7) << 1) | ((b >> 3) & 1);     // XCD(b)=b%8 heuristic
  const int qi = b >> 4;                              // 0..31
  const int bi = qi < 16 ? (31 - qi) : (qi - 16);     // concurrent pairing

  // staging: thread-half sg stages group sg's buffers
  const int sg = t >> 8;
  const int ts = t & 255;
  const int srow = ts >> 3;
  const int ssw  = ((ts & 7) << 4) ^ ((srow & 7) << 4);
  const char* Kg0 = (const char*)Kb + (size_t)(h * S_) * 128;
  const char* Vg0 = (const char*)Vt + (size_t)(h * 64) * (size_t)(S_ * 2);

  const int q0 = bi * 128;
  const int qrow = q0 + w * 32 + lq;
  const int qwmin = q0 + w * 32, qwmax = qwmin + 31;
  const int niter = bi + 1;           // kv tiles per group (blocked split)

  // Q fragments: B-operand of S^T mfma: lane holds Q[q=lq][d0*16 + hi*8 + e]
  const unsigned short* Qr = Qb + ((size_t)(h * S_ + qrow)) * 64;
  bf16x8 qf[4];
#pragma unroll
  for (int d0 = 0; d0 < 4; ++d0)
    qf[d0] = *(const bf16x8*)(Qr + d0 * 16 + hi * 8);

  f32x16 cacc[2] = {};      // ctx^T[d][q], d-blocks 0..31 / 32..63
  float lsum = 0.f;

  auto stage = [&](int buf, int tl) {   // stage tile tl into group sg's buf
    const int kv0 = tl * 64;
    char* kd = smem + sg * 16384 + buf * 8192;
    const char* Kg = Kg0 + (size_t)kv0 * 128;
    gl_lds16(Kg + (size_t)srow * 128 + ssw,        kd + ts * 16);
    gl_lds16(Kg + (size_t)(32 + srow) * 128 + ssw, kd + 4096 + ts * 16);
    char* vd = smem + 32768 + sg * 16384 + buf * 8192;
    const char* Vg = Vg0 + (size_t)kv0 * 2;
    gl_lds16(Vg + (size_t)srow * (S_ * 2) + ssw,        vd + ts * 16);
    gl_lds16(Vg + (size_t)(32 + srow) * (S_ * 2) + ssw, vd + 4096 + ts * 16);
  };

  int cur = 0;
  stage(0, sg * niter);

  for (int it = 0; it < niter; ++it) {
    __syncthreads();
    if (it + 1 < niter) stage(cur ^ 1, it + 1 + sg * niter);
    const char* Kt = smem + g * 16384 + cur * 8192;
    const char* Vl = smem + 32768 + g * 16384 + cur * 8192;
    const int tl = it + g * niter;

    if (tl * 64 + 63 <= qwmin) {
      // ======== FAST PATH: full 64-kv tile, no mask, fused sub-tiles ========
      f32x16 st0, st1;
#pragma unroll
      for (int r = 0; r < 16; ++r) { st0[r] = -8.0f; st1[r] = -8.0f; }
      const char* kb0 = Kt + lq * 128;
      const char* kb1 = Kt + (32 + lq) * 128;
      const int ksw = (lq & 7) << 4;
      __builtin_amdgcn_s_setprio(1);
#pragma unroll
      for (int d0 = 0; d0 < 4; ++d0) {
        bf16x8 kf0 = *(const bf16x8*)(kb0 + ((d0 * 32 + hi * 16) ^ ksw));
        bf16x8 kf1 = *(const bf16x8*)(kb1 + ((d0 * 32 + hi * 16) ^ ksw));
        st0 = mfma32(kf0, qf[d0], st0);
        st1 = mfma32(kf1, qf[d0], st1);
      }
      __builtin_amdgcn_s_setprio(0);

#pragma unroll
      for (int r = 0; r < 16; ++r) { st0[r] = exp2_fast(st0[r]); st1[r] = exp2_fast(st1[r]); }
      float a0 = (st0[0] + st0[1]) + (st0[2] + st0[3]);
      float a1 = (st0[4] + st0[5]) + (st0[6] + st0[7]);
      float a2 = (st0[8] + st0[9]) + (st0[10] + st0[11]);
      float a3 = (st0[12] + st0[13]) + (st0[14] + st0[15]);
      float b0 = (st1[0] + st1[1]) + (st1[2] + st1[3]);
      float b1 = (st1[4] + st1[5]) + (st1[6] + st1[7]);
      float b2 = (st1[8] + st1[9]) + (st1[10] + st1[11]);
      float b3 = (st1[12] + st1[13]) + (st1[14] + st1[15]);
      lsum += xhalf_add(((a0 + a1) + (a2 + a3)) + ((b0 + b1) + (b2 + b3)));

      unsigned x0 = cvtpk(st0[0], st0[1]),   x1 = cvtpk(st0[2], st0[3]);
      unsigned y0 = cvtpk(st0[4], st0[5]),   y1 = cvtpk(st0[6], st0[7]);
      pl32(x0, y0); pl32(x1, y1);
      u32x4 f00 = {x0, x1, y0, y1};
      bf16x8 pf00 = __builtin_bit_cast(bf16x8, f00);
      unsigned x2 = cvtpk(st0[8], st0[9]),   x3 = cvtpk(st0[10], st0[11]);
      unsigned y2 = cvtpk(st0[12], st0[13]), y3 = cvtpk(st0[14], st0[15]);
      pl32(x2, y2); pl32(x3, y3);
      u32x4 f01 = {x2, x3, y2, y3};
      bf16x8 pf01 = __builtin_bit_cast(bf16x8, f01);
      unsigned u0 = cvtpk(st1[0], st1[1]),    u1 = cvtpk(st1[2], st1[3]);
      unsigned v0w = cvtpk(st1[4], st1[5]),   v1w = cvtpk(st1[6], st1[7]);
      pl32(u0, v0w); pl32(u1, v1w);
      u32x4 f10 = {u0, u1, v0w, v1w};
      bf16x8 pf10 = __builtin_bit_cast(bf16x8, f10);
      unsigned u2 = cvtpk(st1[8], st1[9]),    u3 = cvtpk(st1[10], st1[11]);
      unsigned v2w = cvtpk(st1[12], st1[13]), v3w = cvtpk(st1[14], st1[15]);
      pl32(u2, v2w); pl32(u3, v3w);
      u32x4 f11 = {u2, u3, v2w, v3w};
      bf16x8 pf11 = __builtin_bit_cast(bf16x8, f11);

      __builtin_amdgcn_s_setprio(1);
#pragma unroll
      for (int db = 0; db < 2; ++db) {
        const int dr = db * 32 + lq;
        const char* vbase = Vl + dr * 128;
        const int vsw = (dr & 7) << 4;
        bf16x8 va = *(const bf16x8*)(vbase + ((hi * 16) ^ vsw));
        bf16x8 vb = *(const bf16x8*)(vbase + ((32 + hi * 16) ^ vsw));
        bf16x8 vc = *(const bf16x8*)(vbase + ((64 + hi * 16) ^ vsw));
        bf16x8 vd = *(const bf16x8*)(vbase + ((96 + hi * 16) ^ vsw));
        cacc[db] = mfma32(va, pf00, cacc[db]);
        cacc[db] = mfma32(vb, pf01, cacc[db]);
        cacc[db] = mfma32(vc, pf10, cacc[db]);
        cacc[db] = mfma32(vd, pf11, cacc[db]);
      }
      __builtin_amdgcn_s_setprio(0);
    } else {
      // ======== SLOW PATH: diag-straddling / partially skipped tile ========
#pragma unroll
      for (int kvh = 0; kvh < 2; ++kvh) {
        const int kv0s = tl * 64 + kvh * 32;
        if (kv0s > qwmax) continue;   // wave-uniform: fully masked sub-tile

        f32x16 st;
#pragma unroll
        for (int r = 0; r < 16; ++r) st[r] = -8.0f;   // fixed softmax shift
        const int kr = kvh * 32 + lq;
        const char* kbase = Kt + kr * 128;
        const int ksw = (kr & 7) << 4;
#pragma unroll
        for (int d0 = 0; d0 < 4; ++d0) {
          bf16x8 kf = *(const bf16x8*)(kbase + ((d0 * 32 + hi * 16) ^ ksw));
          st = mfma32(kf, qf[d0], st);
        }

        if (kv0s + 31 > qwmin) {
#pragma unroll
          for (int r = 0; r < 16; ++r) {
            const int kvg = kv0s + (r & 3) + 8 * (r >> 2) + 4 * hi;
            if (kvg > qrow) st[r] = -INFINITY;
          }
        }

#pragma unroll
        for (int r = 0; r < 16; ++r) st[r] = exp2_fast(st[r]);
        float a0 = (st[0] + st[1]) + (st[2] + st[3]);
        float a1 = (st[4] + st[5]) + (st[6] + st[7]);
        float a2 = (st[8] + st[9]) + (st[10] + st[11]);
        float a3 = (st[12] + st[13]) + (st[14] + st[15]);
        lsum += xhalf_add((a0 + a1) + (a2 + a3));

        unsigned x0 = cvtpk(st[0], st[1]),   x1 = cvtpk(st[2], st[3]);
        unsigned y0 = cvtpk(st[4], st[5]),   y1 = cvtpk(st[6], st[7]);
        pl32(x0, y0); pl32(x1, y1);
        u32x4 f0 = {x0, x1, y0, y1};
        bf16x8 pf0 = __builtin_bit_cast(bf16x8, f0);
        unsigned x2 = cvtpk(st[8], st[9]),   x3 = cvtpk(st[10], st[11]);
        unsigned y2 = cvtpk(st[12], st[13]), y3 = cvtpk(st[14], st[15]);
        pl32(x2, y2); pl32(x3, y3);
        u32x4 f1 = {x2, x3, y2, y3};
        bf16x8 pf1 = __builtin_bit_cast(bf16x8, f1);

#pragma unroll
        for (int db = 0; db < 2; ++db) {
          const int dr = db * 32 + lq;
          const char* vbase = Vl + dr * 128;
          const int vsw = (dr & 7) << 4;
          bf16x8 v0 = *(const bf16x8*)(vbase + ((kvh * 64 + hi * 16) ^ vsw));
          bf16x8 v1 = *(const bf16x8*)(vbase + ((kvh * 64 + 32 + hi * 16) ^ vsw));
          cacc[db] = mfma32(v0, pf0, cacc[db]);
          cacc[db] = mfma32(v1, pf1, cacc[db]);
        }
      }
    }
    cur ^= 1;
  }

  // ---- combine group partials: plain adds (fixed shift -> no scaling) ----
  __syncthreads();                  // all staged loads drained; overlay safe
  float* slot = (float*)smem + (size_t)(w * 64 + l) * 36;
  if (g == 1) {
    slot[0] = lsum;
#pragma unroll
    for (int j = 0; j < 16; ++j) { slot[1 + j] = cacc[0][j]; slot[17 + j] = cacc[1][j]; }
  }
  __syncthreads();
  if (g == 0) {
    const float inv = 1.0f / (lsum + slot[0]);
    unsigned short* base = ctx + (size_t)qrow * D_ + h * 64;
#pragma unroll
    for (int db = 0; db < 2; ++db)
#pragma unroll
      for (int r = 0; r < 16; r += 2) {
        const float o0 = (cacc[db][r]     + slot[1 + db * 16 + r])     * inv;
        const float o1 = (cacc[db][r + 1] + slot[1 + db * 16 + r + 1]) * inv;
        const unsigned wv = cvtpk(o0, o1);
        const int d = (r & 3) + 8 * (r >> 2) + 4 * hi + 32 * db;
        *(unsigned*)(base + d) = wv;
      }
  }
}

extern "C" void kernel_launch(void* const* d_in, const int* in_sizes, int n_in,
                              void* d_out, int out_size, void* d_ws, size_t ws_size,
                              hipStream_t stream) {
  const float* x      = (const float*)d_in[0];
  const float* Wqkv_w = (const float*)d_in[1];
  const float* Wqkv_b = (const float*)d_in[2];
  const float* out_w  = (const float*)d_in[3];
  const float* out_b  = (const float*)d_in[4];
  float* out = (float*)d_out;
  char* ws = (char*)d_ws;

  unsigned short* xb    = (unsigned short*)(ws + XB_OFF);
  unsigned short* wqkvb = (unsigned short*)(ws + WQKV_OFF);
  unsigned short* woutb = (unsigned short*)(ws + WOUT_OFF);
  unsigned short* Qb    = (unsigned short*)(ws + QB_OFF);
  unsigned short* Kb    = (unsigned short*)(ws + KB_OFF);
  unsigned short* Vt    = (unsigned short*)(ws + VT_OFF);
  unsigned short* ctx   = (unsigned short*)(ws + CTX_OFF);

  cvt_all_k<<<2048, 256, 0, stream>>>(x, Wqkv_w, out_w, xb, wqkvb, woutb);

  gemm_qkv_k<<<dim3(24, 32), 512, 0, stream>>>(xb, wqkvb, Wqkv_b, Qb, Kb, Vt);

  attn_k<<<dim3(32, 16), 512, 0, stream>>>(Qb, Kb, Vt, ctx);

  gemm_proj_k<<<dim3(16, 32), 512, 0, stream>>>(ctx, woutb, out_b, out);
}